// Round 11
// baseline (195.872 us; speedup 1.0000x reference)
//
#include <hip/hip_runtime.h>

#define FIN 100
#define FHID 100
#define FEMB 64
#define NCLS 40
#define H1STR 112             // padded row stride for h1: 14 x ushort8, 224B rows (pad cols 100..111 zeroed)

#define SBSH 8                // 256 nodes per super-bucket
#define CAPB 24               // LDS bin capacity per block (EPB=2048: mean 10.4 -> overflow ~1e-4, order-stable)
#define SBCAP 4608            // per-super-bucket arena cap: mean 4096 + 8 sigma
#define CSTR 16               // cursor stride in ints
#define EPB 2048              // edges per scatter block (R5 value)

typedef __attribute__((ext_vector_type(8))) short short8;          // MFMA A/B frag
typedef __attribute__((ext_vector_type(8))) unsigned short u16x8;  // 16B bf16 gather
typedef __attribute__((ext_vector_type(4))) float f32x4;           // MFMA C/D frag

// ---------- bf16 helpers (RNE) ----------
__device__ inline unsigned short f2bf(float f) {
    unsigned u = __float_as_uint(f);
    u += 0x7FFFu + ((u >> 16) & 1u);
    return (unsigned short)(u >> 16);
}
__device__ inline float bf2f(unsigned short s) {
    return __uint_as_float((unsigned)s << 16);
}

// ====== 4-wave MFMA tiles (GEMM1 inside k_front; 256 threads, multi-pass) ======
template <int KP, int KOUT, int NTY, bool BIAS, bool OUT_BF16, int OSTR>
__device__ __forceinline__ void mfma_tiles4(const unsigned short* Abf, const unsigned short* Wt,
                                            const float* __restrict__ bias, void* __restrict__ C,
                                            int n, int row0, int tb) {
    constexpr int APAD  = KP + 8;
    constexpr int NKC   = KP / 32;
    constexpr int TQ    = (NTY + 1) / 2;
    constexpr int NTALL = (KOUT + 15) / 16;

    const int tid  = threadIdx.x;
    const int lane = tid & 63;
    const int w    = tid >> 6;
    const int m0   = (w >> 1) * 64;
    const int t0   = (w & 1) * TQ;
    const int lm   = lane & 15;
    const int quad = lane >> 4;

    const int ntloc = (NTALL - tb < NTY) ? (NTALL - tb) : NTY;
    const int tcnt  = (ntloc - t0 < TQ) ? (ntloc - t0) : TQ;

    f32x4 acc[4][TQ];
    #pragma unroll
    for (int i = 0; i < 4; ++i)
        #pragma unroll
        for (int t = 0; t < TQ; ++t)
            acc[i][t] = (f32x4)(0.f);

    for (int kt = 0; kt < NKC; ++kt) {
        short8 a[4], b[TQ];
        #pragma unroll
        for (int i = 0; i < 4; ++i)
            a[i] = *(const short8*)&Abf[(m0 + i * 16 + lm) * APAD + kt * 32 + quad * 8];
        #pragma unroll
        for (int t = 0; t < TQ; ++t)
            if (t < tcnt)
                b[t] = *(const short8*)&Wt[((t0 + t) * 16 + lm) * APAD + kt * 32 + quad * 8];
        #pragma unroll
        for (int i = 0; i < 4; ++i)
            #pragma unroll
            for (int t = 0; t < TQ; ++t)
                if (t < tcnt)
                    acc[i][t] = __builtin_amdgcn_mfma_f32_16x16x32_bf16(a[i], b[t], acc[i][t], 0, 0, 0);
    }

    #pragma unroll
    for (int t = 0; t < TQ; ++t) {
        if (t >= tcnt) continue;
        int col = (tb + t0 + t) * 16 + lm;
        if (col >= KOUT) continue;
        float bv = 0.f;
        if constexpr (BIAS) bv = bias[col];
        #pragma unroll
        for (int i = 0; i < 4; ++i) {
            #pragma unroll
            for (int rg = 0; rg < 4; ++rg) {
                int row = row0 + m0 + i * 16 + quad * 4 + rg;
                if (row < n) {
                    float v = acc[i][t][rg] + bv;
                    if constexpr (OUT_BF16)
                        ((unsigned short*)C)[(size_t)row * OSTR + col] = f2bf(v);
                    else
                        ((float*)C)[(size_t)row * OSTR + col] = v;
                }
            }
        }
    }
}

// ====== GEMM1 body: stage fp32 A -> bf16 LDS, multi-pass Wt, 256 threads ======
template <int KIN, int KOUT, int NTY, bool OUT_BF16, int ASTR, int OSTR>
__device__ __forceinline__ void gemm_body(const void* __restrict__ A, const float* __restrict__ W,
                                          void* __restrict__ C, int n, int bid, char* smem) {
    constexpr int KP    = ((KIN + 31) / 32) * 32;
    constexpr int NTALL = (KOUT + 15) / 16;
    constexpr int NTC   = NTY * 16;
    constexpr int APAD  = KP + 8;
    constexpr int KQ4   = KIN / 4;

    unsigned short* Abf = (unsigned short*)smem;               // 128 * APAD
    unsigned short* Wt  = Abf + 128 * APAD;                    // NTC * APAD

    const int row0 = bid * 128;
    const int tid  = threadIdx.x;

    {   // stage A (fp32 -> bf16)
        const float* Af = (const float*)A;
        for (int idx = tid; idx < 128 * KQ4; idx += 256) {
            int r = idx / KQ4;
            int kq = idx - r * KQ4;
            float4 v = make_float4(0.f, 0.f, 0.f, 0.f);
            if (row0 + r < n) v = ((const float4*)(Af + (size_t)(row0 + r) * ASTR))[kq];
            ushort4 o;
            o.x = f2bf(v.x); o.y = f2bf(v.y); o.z = f2bf(v.z); o.w = f2bf(v.w);
            *(ushort4*)&Abf[r * APAD + kq * 4] = o;
        }
    }
    if constexpr (KP > KIN) {
        constexpr int PADW = KP - KIN;
        for (int idx = tid; idx < 128 * PADW; idx += 256) {
            int r = idx / PADW;
            Abf[r * APAD + KIN + (idx - r * PADW)] = 0;
        }
    }
    // zero output pad columns (downstream u16x8 gathers read exact zeros)
    if constexpr (OUT_BF16 && (OSTR > KOUT)) {
        constexpr int PW = OSTR - KOUT;
        for (int idx = tid; idx < 128 * PW; idx += 256) {
            int r = idx / PW;
            int c = idx - r * PW;
            if (row0 + r < n)
                ((unsigned short*)C)[(size_t)(row0 + r) * OSTR + KOUT + c] = 0;
        }
    }

    for (int tb = 0; tb < NTALL; tb += NTY) {
        for (int idx = tid; idx < KIN * NTC; idx += 256) {
            int k = idx / NTC;
            int c = idx - k * NTC;
            int gc = tb * 16 + c;
            float v = (gc < KOUT) ? W[(size_t)k * KOUT + gc] : 0.f;
            Wt[c * APAD + k] = f2bf(v);
        }
        if constexpr (KP > KIN) {
            constexpr int PADW = KP - KIN;
            for (int idx = tid; idx < NTC * PADW; idx += 256) {
                int c = idx / PADW;
                Wt[c * APAD + KIN + (idx - c * PADW)] = 0;
            }
        }
        __syncthreads();
        mfma_tiles4<KP, KOUT, NTY, false, OUT_BF16, OSTR>(Abf, Wt, nullptr, C, n, row0, tb);
        __syncthreads();
    }
}

// ====== merged front: edge scatter-binning (blocks [0,scb)) || GEMM1 (blocks [scb,scb+nmb)) ======
// R5-verbatim.
#define SMEM_FRONT ((128 + 64) * (128 + 8) * 2)   // 52224B; gemm1 is the larger user
__global__ __launch_bounds__(256) void k_front(const int* __restrict__ src,
                                               const int* __restrict__ dst,
                                               int* __restrict__ gcur,
                                               int* __restrict__ arena,
                                               int E, int nsb, int scb,
                                               const float* __restrict__ x,
                                               const float* __restrict__ W1,
                                               unsigned short* __restrict__ h1, int n) {
    __shared__ __attribute__((aligned(16))) char smem[SMEM_FRONT];
    static_assert(SMEM_FRONT >= (int)(256 * CAPB * 4 + 2 * 256 * 4), "scatter fits");
    if ((int)blockIdx.x < scb) {
        int* bins  = (int*)smem;            // 256*CAPB
        int* bcnt  = bins + 256 * CAPB;     // 256
        int* pbase = bcnt + 256;            // 256
        const int tid = threadIdx.x;
        bcnt[tid] = 0;
        __syncthreads();

        const int e0 = blockIdx.x * EPB;
        for (int k = 0; k < EPB / 256; ++k) {
            int e = e0 + k * 256 + tid;
            if (e < E) {
                int d = dst[e];
                int sb = d >> SBSH;
                int rec = (src[e] << SBSH) | (d & 255);
                int c = atomicAdd(&bcnt[sb], 1);
                if (c < CAPB) {
                    bins[sb * CAPB + c] = rec;
                } else {  // rare overflow: direct global append
                    int p = atomicAdd(&gcur[sb * CSTR], 1);
                    if (p < SBCAP) arena[(size_t)sb * SBCAP + p] = rec;
                }
            }
        }
        __syncthreads();

        if (tid < nsb) {
            int c = bcnt[tid];
            if (c > CAPB) c = CAPB;
            pbase[tid] = (c > 0) ? atomicAdd(&gcur[tid * CSTR], c) : 0;
        }
        __syncthreads();

        const int wv = tid >> 6, lane = tid & 63;
        for (int sb = wv; sb < nsb; sb += 4) {
            int c = bcnt[sb];
            if (c > CAPB) c = CAPB;
            int p = pbase[sb];
            if (lane < c && p + lane < SBCAP)
                arena[(size_t)sb * SBCAP + p + lane] = bins[sb * CAPB + lane];
        }
    } else {
        gemm_body<FIN, FHID, 4, true, FIN, H1STR>(x, W1, h1, n, (int)blockIdx.x - scb, smem);
    }
}

// ====== per-super-bucket sort: 1024 threads (verified R1/R5/R10) ======
__global__ __launch_bounds__(1024) void k_bucket_sort(const int* __restrict__ arena,
                                                      const int* __restrict__ gcur,
                                                      int* __restrict__ gcounter,
                                                      int* __restrict__ rowptr,
                                                      int* __restrict__ rowend,
                                                      float* __restrict__ dinv,
                                                      int* __restrict__ src_sorted, int n) {
    const int sb = blockIdx.x;
    const int tid = threadIdx.x;
    __shared__ int cnt[256], off[256], tmp[256];
    __shared__ int base_sh;
    if (tid < 256) cnt[tid] = 0;
    __syncthreads();

    int len = gcur[sb * CSTR];
    if (len > SBCAP) len = SBCAP;
    const int* seg = arena + (size_t)sb * SBCAP;
    for (int i = tid; i < len; i += 1024)
        atomicAdd(&cnt[seg[i] & 255], 1);
    __syncthreads();

    int v = 0;
    if (tid < 256) { v = cnt[tid]; tmp[tid] = v; }
    __syncthreads();
    for (int o = 1; o < 256; o <<= 1) {
        int t = (tid >= o && tid < 256) ? tmp[tid - o] : 0;
        __syncthreads();
        if (tid < 256) tmp[tid] += t;
        __syncthreads();
    }
    if (tid < 256) off[tid] = tmp[tid] - v;  // exclusive
    if (tid == 255) base_sh = atomicAdd(gcounter, tmp[255]);
    __syncthreads();

    const int base = base_sh;
    if (tid < 256) {
        int node = (sb << SBSH) + tid;
        if (node < n) {
            int r0 = base + off[tid];
            rowptr[node] = r0;
            rowend[node] = r0 + v;
            dinv[node] = rsqrtf((float)v + 1.0f);  // +1 self-loop
        }
    }
    __syncthreads();

    for (int i = tid; i < len; i += 1024) {
        int rec = seg[i];
        int lpos = atomicAdd(&off[rec & 255], 1);
        src_sorted[base + lpos] = rec >> SBSH;
    }
}

// ====== 8-wave single-pass MFMA tiles (64-row blocks; same fragment mapping as verified tiles16) ======
template <int KP, int KOUT, int NTY, bool BIAS, bool OUT_BF16, int OSTR>
__device__ __forceinline__ void mfma_tiles8(const unsigned short* Abf, const unsigned short* Wt,
                                            const float* __restrict__ bias, void* __restrict__ C,
                                            int n, int row0) {
    constexpr int APAD  = KP + 8;
    constexpr int NKC   = KP / 32;
    constexpr int TQ    = (NTY + 1) / 2;
    constexpr int NTALL = (KOUT + 15) / 16;

    const int tid  = threadIdx.x;
    const int lane = tid & 63;
    const int w    = tid >> 6;          // 0..7
    const int m0   = (w >> 1) * 16;     // 16-row strip per wave pair (4 strips = 64 rows)
    const int t0   = (w & 1) * TQ;
    const int lm   = lane & 15;
    const int quad = lane >> 4;
    const int tcnt = (NTALL - t0 < TQ) ? (NTALL - t0) : TQ;

    f32x4 acc[TQ];
    #pragma unroll
    for (int t = 0; t < TQ; ++t) acc[t] = (f32x4)(0.f);

    for (int kt = 0; kt < NKC; ++kt) {
        short8 a = *(const short8*)&Abf[(m0 + lm) * APAD + kt * 32 + quad * 8];
        short8 b[TQ];
        #pragma unroll
        for (int t = 0; t < TQ; ++t)
            if (t < tcnt)
                b[t] = *(const short8*)&Wt[((t0 + t) * 16 + lm) * APAD + kt * 32 + quad * 8];
        #pragma unroll
        for (int t = 0; t < TQ; ++t)
            if (t < tcnt)
                acc[t] = __builtin_amdgcn_mfma_f32_16x16x32_bf16(a, b[t], acc[t], 0, 0, 0);
    }

    #pragma unroll
    for (int t = 0; t < TQ; ++t) {
        if (t >= tcnt) continue;
        int col = (t0 + t) * 16 + lm;
        if (col >= KOUT) continue;
        float bv = 0.f;
        if constexpr (BIAS) bv = bias[col];
        #pragma unroll
        for (int rg = 0; rg < 4; ++rg) {
            int row = row0 + m0 + quad * 4 + rg;
            if (row < n) {
                float v = acc[t][rg] + bv;
                if constexpr (OUT_BF16)
                    ((unsigned short*)C)[(size_t)row * OSTR + col] = f2bf(v);
                else
                    ((float*)C)[(size_t)row * OSTR + col] = v;
            }
        }
    }
}

// ====== fused gather-aggregation + GEMM: 64-row / 512-thread blocks, unroll-8 gathers ======
// vs R10 (verified): (a) block covers 64 rows with 8 waves (finer CU load balance, same total
// waves); (b) gather loop issues 8 batches in flight before consuming (more MLP).  Both changes
// preserve per-row FMA order EXACTLY (edges consumed sequentially in CSR order) -> bit-identical
// output to R10.
template <int FAGG, int NG, int HSTR, int KIN, int KOUT, int NTY, bool GBIAS, bool OUT_BF16, int OSTR>
__global__ __launch_bounds__(512) void k_agg_gemm(const unsigned short* __restrict__ h,
                                                  const int* __restrict__ rowptr,
                                                  const int* __restrict__ rowend,
                                                  const int* __restrict__ src_sorted,
                                                  const float* __restrict__ dinv,
                                                  const float* __restrict__ ab,
                                                  const float* __restrict__ W,
                                                  const float* __restrict__ gb,
                                                  void* __restrict__ C, int n) {
    constexpr int KP   = ((KIN + 31) / 32) * 32;
    constexpr int APAD = KP + 8;
    constexpr int NTC  = NTY * 16;
    static_assert(NTC >= ((KOUT + 15) / 16) * 16, "single-pass Wt");
    static_assert(NG * 8 <= KP, "agg cols fit A tile");

    __shared__ __attribute__((aligned(16))) unsigned short Abf[64 * APAD];
    __shared__ __attribute__((aligned(16))) unsigned short Wt[NTC * APAD];
    __shared__ int   rp0[64], rc[64];   // per-row CSR start / count (absolute indices)
    __shared__ float sdi[64];           // per-row dinv[i]

    const int tid  = threadIdx.x;
    const int row0 = blockIdx.x * 64;

    // ---- (1) stage Wt (+k pads) + per-row scalars ----
    for (int idx = tid; idx < KIN * NTC; idx += 512) {
        int k = idx / NTC;
        int c = idx - k * NTC;
        float v = (c < KOUT) ? W[(size_t)k * KOUT + c] : 0.f;
        Wt[c * APAD + k] = f2bf(v);
    }
    if constexpr (KP > KIN) {
        constexpr int PADW = KP - KIN;
        for (int idx = tid; idx < NTC * PADW; idx += 512) {
            int c = idx / PADW;
            Wt[c * APAD + KIN + (idx - c * PADW)] = 0;
        }
    }
    if (tid < 64) {
        int i = row0 + tid;
        if (i < n) {
            int r0 = rowptr[i];
            rp0[tid] = r0;
            rc[tid]  = rowend[i] - r0;
            sdi[tid] = dinv[i];
        } else {
            rp0[tid] = 0; rc[tid] = 0; sdi[tid] = 0.f;
        }
    }
    __syncthreads();

    // ---- (2) gather-aggregate into Abf (bit-exact CSR-order accumulation) ----
    for (int idx = tid; idx < 64 * NG; idx += 512) {
        int r = idx / NG;
        int g = idx - r * NG;
        const int co = g * 8;
        int i = row0 + r;
        u16x8 o;
        #pragma unroll
        for (int j = 0; j < 8; ++j) o[j] = 0;
        if (i < n) {
            const unsigned short* hp = h + co;
            float a[8];
            #pragma unroll
            for (int j = 0; j < 8; ++j) a[j] = 0.f;
            int e = rp0[r];
            const int end = e + rc[r];
            // unroll-8: 8 gathers in flight before first consume; consumed in e-order
            for (; e + 7 < end; e += 8) {
                int s0 = src_sorted[e],     s1 = src_sorted[e + 1];
                int s2 = src_sorted[e + 2], s3 = src_sorted[e + 3];
                int s4 = src_sorted[e + 4], s5 = src_sorted[e + 5];
                int s6 = src_sorted[e + 6], s7 = src_sorted[e + 7];
                u16x8 u0 = *(const u16x8*)&hp[(size_t)s0 * HSTR];
                u16x8 u1 = *(const u16x8*)&hp[(size_t)s1 * HSTR];
                u16x8 u2 = *(const u16x8*)&hp[(size_t)s2 * HSTR];
                u16x8 u3 = *(const u16x8*)&hp[(size_t)s3 * HSTR];
                u16x8 u4 = *(const u16x8*)&hp[(size_t)s4 * HSTR];
                u16x8 u5 = *(const u16x8*)&hp[(size_t)s5 * HSTR];
                u16x8 u6 = *(const u16x8*)&hp[(size_t)s6 * HSTR];
                u16x8 u7 = *(const u16x8*)&hp[(size_t)s7 * HSTR];
                float n0 = dinv[s0], n1 = dinv[s1], n2 = dinv[s2], n3 = dinv[s3];
                float n4 = dinv[s4], n5 = dinv[s5], n6 = dinv[s6], n7 = dinv[s7];
                #pragma unroll
                for (int j = 0; j < 8; ++j) {
                    a[j] = fmaf(bf2f(u0[j]), n0, a[j]);
                    a[j] = fmaf(bf2f(u1[j]), n1, a[j]);
                    a[j] = fmaf(bf2f(u2[j]), n2, a[j]);
                    a[j] = fmaf(bf2f(u3[j]), n3, a[j]);
                    a[j] = fmaf(bf2f(u4[j]), n4, a[j]);
                    a[j] = fmaf(bf2f(u5[j]), n5, a[j]);
                    a[j] = fmaf(bf2f(u6[j]), n6, a[j]);
                    a[j] = fmaf(bf2f(u7[j]), n7, a[j]);
                }
            }
            for (; e + 3 < end; e += 4) {
                int s0 = src_sorted[e],     s1 = src_sorted[e + 1];
                int s2 = src_sorted[e + 2], s3 = src_sorted[e + 3];
                u16x8 u0 = *(const u16x8*)&hp[(size_t)s0 * HSTR];
                u16x8 u1 = *(const u16x8*)&hp[(size_t)s1 * HSTR];
                u16x8 u2 = *(const u16x8*)&hp[(size_t)s2 * HSTR];
                u16x8 u3 = *(const u16x8*)&hp[(size_t)s3 * HSTR];
                float n0 = dinv[s0], n1 = dinv[s1], n2 = dinv[s2], n3 = dinv[s3];
                #pragma unroll
                for (int j = 0; j < 8; ++j) {
                    a[j] = fmaf(bf2f(u0[j]), n0, a[j]);
                    a[j] = fmaf(bf2f(u1[j]), n1, a[j]);
                    a[j] = fmaf(bf2f(u2[j]), n2, a[j]);
                    a[j] = fmaf(bf2f(u3[j]), n3, a[j]);
                }
            }
            for (; e < end; ++e) {
                int s = src_sorted[e];
                u16x8 u = *(const u16x8*)&hp[(size_t)s * HSTR];
                float nn = dinv[s];
                #pragma unroll
                for (int j = 0; j < 8; ++j) a[j] = fmaf(bf2f(u[j]), nn, a[j]);
            }
            float di = sdi[r];
            u16x8 hs = *(const u16x8*)&hp[(size_t)i * HSTR];
            #pragma unroll
            for (int j = 0; j < 8; ++j) {
                int col = co + j;
                float bj = (col < FAGG) ? ab[col] : 0.f;
                float vv = fmaf(di, fmaf(di, bf2f(hs[j]), a[j]), bj);
                o[j] = f2bf(fmaxf(vv, 0.f));
            }
        }
        *(u16x8*)&Abf[r * APAD + co] = o;
    }
    if constexpr (KP > NG * 8) {             // zero A pad cols [NG*8, KP)
        constexpr int PW = KP - NG * 8;
        for (int idx = tid; idx < 64 * PW; idx += 512) {
            int r = idx / PW;
            Abf[r * APAD + NG * 8 + (idx - r * PW)] = 0;
        }
    }
    __syncthreads();

    // ---- (3) GEMM ----
    mfma_tiles8<KP, KOUT, NTY, GBIAS, OUT_BF16, OSTR>(Abf, Wt, gb, C, n, row0);
}

extern "C" void kernel_launch(void* const* d_in, const int* in_sizes, int n_in,
                              void* d_out, int out_size, void* d_ws, size_t ws_size,
                              hipStream_t stream) {
    const float* x  = (const float*)d_in[0];
    const int*   ei = (const int*)d_in[1];
    const float* W1 = (const float*)d_in[2];
    const float* b1 = (const float*)d_in[3];
    const float* W2 = (const float*)d_in[4];
    const float* b2 = (const float*)d_in[5];
    const float* Wc = (const float*)d_in[6];
    const float* bc = (const float*)d_in[7];
    float* out = (float*)d_out;

    const int N = in_sizes[0] / FIN;
    const int E = in_sizes[1] / 2;
    const int* src = ei;
    const int* dst = ei + E;
    const int NSB = (N + 255) >> SBSH;       // 196
    const int SCB = (E + EPB - 1) / EPB;     // 391

    auto align = [](size_t v) { return (v + 255) & ~(size_t)255; };
    char* ws = (char*)d_ws;
    const size_t cur_bytes = align((size_t)256 * CSTR * 4 + 256);
    int*   gcur       = (int*)ws;   ws += cur_bytes;
    int*   gcounter   = gcur + 256 * CSTR;   // inside the memset region
    int*   arena      = (int*)ws;   ws += align((size_t)NSB * SBCAP * 4);
    int*   rowptr     = (int*)ws;   ws += align((size_t)N * 4);
    int*   rowend     = (int*)ws;   ws += align((size_t)N * 4);
    int*   src_sorted = (int*)ws;   ws += align((size_t)E * 4);
    float* dinv       = (float*)ws; ws += align((size_t)N * 4);
    unsigned short* h1 = (unsigned short*)ws; ws += align((size_t)N * H1STR * 2);
    unsigned short* h2 = (unsigned short*)ws; ws += align((size_t)N * FEMB * 2);

    const int nmb   = (N + 127) / 128;       // 391 GEMM1 row-tiles
    const int nmb64 = (N + 63) / 64;         // 782 fused row-tiles

    // 1) zero cursors + gcounter
    hipMemsetAsync(gcur, 0, cur_bytes, stream);

    // 2) merged: edge scatter (blocks [0,SCB)) || GEMM1 h1 = x@W1 (blocks [SCB,SCB+nmb))
    k_front<<<SCB + nmb, 256, 0, stream>>>(src, dst, gcur, arena, E, NSB, SCB, x, W1, h1, N);

    // 3) per-super-bucket sort -> rowptr/rowend/dinv/src_sorted
    k_bucket_sort<<<NSB, 1024, 0, stream>>>(arena, gcur, gcounter, rowptr, rowend, dinv, src_sorted, N);

    // 4) fused: a1 = relu(agg(h1)+b1) -> LDS; h2 = a1 @ W2 (bf16, stride FEMB)
    k_agg_gemm<FHID, 13, H1STR, FHID, FEMB, 4, false, true, FEMB>
        <<<nmb64, 512, 0, stream>>>(h1, rowptr, rowend, src_sorted, dinv, b1, W2, nullptr, h2, N);

    // 5) fused: a2 = relu(agg(h2)+b2) -> LDS; out = a2 @ Wc + bc (fp32)
    k_agg_gemm<FEMB, 8, FEMB, FEMB, NCLS, 3, true, false, NCLS>
        <<<nmb64, 512, 0, stream>>>(h2, rowptr, rowend, src_sorted, dinv, b2, Wc, bc, out, N);
}

// Round 12
// 192.512 us; speedup vs baseline: 1.0175x; 1.0175x over previous
//
#include <hip/hip_runtime.h>

#define FIN 100
#define FHID 100
#define FEMB 64
#define NCLS 40
#define H1STR 128             // h1 row stride: 256B, line-ALIGNED (was 112/224B, straddled 2-3 lines)

#define SBSH 8                // 256 nodes per super-bucket
#define CAPB 24               // LDS bin capacity per block (EPB=2048: mean 10.4 -> overflow ~1e-4, order-stable)
#define SBCAP 4608            // per-super-bucket arena cap: mean 4096 + 8 sigma
#define CSTR 16               // cursor stride in ints
#define EPB 2048              // edges per scatter block (R5 value)

typedef __attribute__((ext_vector_type(8))) short short8;          // MFMA A/B frag
typedef __attribute__((ext_vector_type(8))) unsigned short u16x8;  // 16B bf16 gather
typedef __attribute__((ext_vector_type(4))) float f32x4;           // MFMA C/D frag

// ---------- bf16 helpers (RNE) ----------
__device__ inline unsigned short f2bf(float f) {
    unsigned u = __float_as_uint(f);
    u += 0x7FFFu + ((u >> 16) & 1u);
    return (unsigned short)(u >> 16);
}
__device__ inline float bf2f(unsigned short s) {
    return __uint_as_float((unsigned)s << 16);
}

// ====== 4-wave MFMA tiles (GEMM1 inside k_front; 256 threads, multi-pass) ======
template <int KP, int KOUT, int NTY, bool BIAS, bool OUT_BF16, int OSTR>
__device__ __forceinline__ void mfma_tiles4(const unsigned short* Abf, const unsigned short* Wt,
                                            const float* __restrict__ bias, void* __restrict__ C,
                                            int n, int row0, int tb) {
    constexpr int APAD  = KP + 8;
    constexpr int NKC   = KP / 32;
    constexpr int TQ    = (NTY + 1) / 2;
    constexpr int NTALL = (KOUT + 15) / 16;

    const int tid  = threadIdx.x;
    const int lane = tid & 63;
    const int w    = tid >> 6;
    const int m0   = (w >> 1) * 64;
    const int t0   = (w & 1) * TQ;
    const int lm   = lane & 15;
    const int quad = lane >> 4;

    const int ntloc = (NTALL - tb < NTY) ? (NTALL - tb) : NTY;
    const int tcnt  = (ntloc - t0 < TQ) ? (ntloc - t0) : TQ;

    f32x4 acc[4][TQ];
    #pragma unroll
    for (int i = 0; i < 4; ++i)
        #pragma unroll
        for (int t = 0; t < TQ; ++t)
            acc[i][t] = (f32x4)(0.f);

    for (int kt = 0; kt < NKC; ++kt) {
        short8 a[4], b[TQ];
        #pragma unroll
        for (int i = 0; i < 4; ++i)
            a[i] = *(const short8*)&Abf[(m0 + i * 16 + lm) * APAD + kt * 32 + quad * 8];
        #pragma unroll
        for (int t = 0; t < TQ; ++t)
            if (t < tcnt)
                b[t] = *(const short8*)&Wt[((t0 + t) * 16 + lm) * APAD + kt * 32 + quad * 8];
        #pragma unroll
        for (int i = 0; i < 4; ++i)
            #pragma unroll
            for (int t = 0; t < TQ; ++t)
                if (t < tcnt)
                    acc[i][t] = __builtin_amdgcn_mfma_f32_16x16x32_bf16(a[i], b[t], acc[i][t], 0, 0, 0);
    }

    #pragma unroll
    for (int t = 0; t < TQ; ++t) {
        if (t >= tcnt) continue;
        int col = (tb + t0 + t) * 16 + lm;
        if (col >= KOUT) continue;
        float bv = 0.f;
        if constexpr (BIAS) bv = bias[col];
        #pragma unroll
        for (int i = 0; i < 4; ++i) {
            #pragma unroll
            for (int rg = 0; rg < 4; ++rg) {
                int row = row0 + m0 + i * 16 + quad * 4 + rg;
                if (row < n) {
                    float v = acc[i][t][rg] + bv;
                    if constexpr (OUT_BF16)
                        ((unsigned short*)C)[(size_t)row * OSTR + col] = f2bf(v);
                    else
                        ((float*)C)[(size_t)row * OSTR + col] = v;
                }
            }
        }
    }
}

// ====== GEMM1 body: stage fp32 A -> bf16 LDS, multi-pass Wt, 256 threads ======
template <int KIN, int KOUT, int NTY, bool OUT_BF16, int ASTR, int OSTR>
__device__ __forceinline__ void gemm_body(const void* __restrict__ A, const float* __restrict__ W,
                                          void* __restrict__ C, int n, int bid, char* smem) {
    constexpr int KP    = ((KIN + 31) / 32) * 32;
    constexpr int NTALL = (KOUT + 15) / 16;
    constexpr int NTC   = NTY * 16;
    constexpr int APAD  = KP + 8;
    constexpr int KQ4   = KIN / 4;

    unsigned short* Abf = (unsigned short*)smem;               // 128 * APAD
    unsigned short* Wt  = Abf + 128 * APAD;                    // NTC * APAD

    const int row0 = bid * 128;
    const int tid  = threadIdx.x;

    {   // stage A (fp32 -> bf16)
        const float* Af = (const float*)A;
        for (int idx = tid; idx < 128 * KQ4; idx += 256) {
            int r = idx / KQ4;
            int kq = idx - r * KQ4;
            float4 v = make_float4(0.f, 0.f, 0.f, 0.f);
            if (row0 + r < n) v = ((const float4*)(Af + (size_t)(row0 + r) * ASTR))[kq];
            ushort4 o;
            o.x = f2bf(v.x); o.y = f2bf(v.y); o.z = f2bf(v.z); o.w = f2bf(v.w);
            *(ushort4*)&Abf[r * APAD + kq * 4] = o;
        }
    }
    if constexpr (KP > KIN) {
        constexpr int PADW = KP - KIN;
        for (int idx = tid; idx < 128 * PADW; idx += 256) {
            int r = idx / PADW;
            Abf[r * APAD + KIN + (idx - r * PADW)] = 0;
        }
    }
    // zero output pad columns (downstream u16x8 gathers read exact zeros)
    if constexpr (OUT_BF16 && (OSTR > KOUT)) {
        constexpr int PW = OSTR - KOUT;
        for (int idx = tid; idx < 128 * PW; idx += 256) {
            int r = idx / PW;
            int c = idx - r * PW;
            if (row0 + r < n)
                ((unsigned short*)C)[(size_t)(row0 + r) * OSTR + KOUT + c] = 0;
        }
    }

    for (int tb = 0; tb < NTALL; tb += NTY) {
        for (int idx = tid; idx < KIN * NTC; idx += 256) {
            int k = idx / NTC;
            int c = idx - k * NTC;
            int gc = tb * 16 + c;
            float v = (gc < KOUT) ? W[(size_t)k * KOUT + gc] : 0.f;
            Wt[c * APAD + k] = f2bf(v);
        }
        if constexpr (KP > KIN) {
            constexpr int PADW = KP - KIN;
            for (int idx = tid; idx < NTC * PADW; idx += 256) {
                int c = idx / PADW;
                Wt[c * APAD + KIN + (idx - c * PADW)] = 0;
            }
        }
        __syncthreads();
        mfma_tiles4<KP, KOUT, NTY, false, OUT_BF16, OSTR>(Abf, Wt, nullptr, C, n, row0, tb);
        __syncthreads();
    }
}

// ====== merged front: edge scatter-binning (blocks [0,scb)) || GEMM1 (blocks [scb,scb+nmb)) ======
// R5-verbatim.
#define SMEM_FRONT ((128 + 64) * (128 + 8) * 2)   // 52224B; gemm1 is the larger user
__global__ __launch_bounds__(256) void k_front(const int* __restrict__ src,
                                               const int* __restrict__ dst,
                                               int* __restrict__ gcur,
                                               int* __restrict__ arena,
                                               int E, int nsb, int scb,
                                               const float* __restrict__ x,
                                               const float* __restrict__ W1,
                                               unsigned short* __restrict__ h1, int n) {
    __shared__ __attribute__((aligned(16))) char smem[SMEM_FRONT];
    static_assert(SMEM_FRONT >= (int)(256 * CAPB * 4 + 2 * 256 * 4), "scatter fits");
    if ((int)blockIdx.x < scb) {
        int* bins  = (int*)smem;            // 256*CAPB
        int* bcnt  = bins + 256 * CAPB;     // 256
        int* pbase = bcnt + 256;            // 256
        const int tid = threadIdx.x;
        bcnt[tid] = 0;
        __syncthreads();

        const int e0 = blockIdx.x * EPB;
        for (int k = 0; k < EPB / 256; ++k) {
            int e = e0 + k * 256 + tid;
            if (e < E) {
                int d = dst[e];
                int sb = d >> SBSH;
                int rec = (src[e] << SBSH) | (d & 255);
                int c = atomicAdd(&bcnt[sb], 1);
                if (c < CAPB) {
                    bins[sb * CAPB + c] = rec;
                } else {  // rare overflow: direct global append
                    int p = atomicAdd(&gcur[sb * CSTR], 1);
                    if (p < SBCAP) arena[(size_t)sb * SBCAP + p] = rec;
                }
            }
        }
        __syncthreads();

        if (tid < nsb) {
            int c = bcnt[tid];
            if (c > CAPB) c = CAPB;
            pbase[tid] = (c > 0) ? atomicAdd(&gcur[tid * CSTR], c) : 0;
        }
        __syncthreads();

        const int wv = tid >> 6, lane = tid & 63;
        for (int sb = wv; sb < nsb; sb += 4) {
            int c = bcnt[sb];
            if (c > CAPB) c = CAPB;
            int p = pbase[sb];
            if (lane < c && p + lane < SBCAP)
                arena[(size_t)sb * SBCAP + p + lane] = bins[sb * CAPB + lane];
        }
    } else {
        gemm_body<FIN, FHID, 4, true, FIN, H1STR>(x, W1, h1, n, (int)blockIdx.x - scb, smem);
    }
}

// ====== per-super-bucket sort: 1024 threads (verified R1/R5/R10) ======
__global__ __launch_bounds__(1024) void k_bucket_sort(const int* __restrict__ arena,
                                                      const int* __restrict__ gcur,
                                                      int* __restrict__ gcounter,
                                                      int* __restrict__ rowptr,
                                                      int* __restrict__ rowend,
                                                      float* __restrict__ dinv,
                                                      int* __restrict__ src_sorted, int n) {
    const int sb = blockIdx.x;
    const int tid = threadIdx.x;
    __shared__ int cnt[256], off[256], tmp[256];
    __shared__ int base_sh;
    if (tid < 256) cnt[tid] = 0;
    __syncthreads();

    int len = gcur[sb * CSTR];
    if (len > SBCAP) len = SBCAP;
    const int* seg = arena + (size_t)sb * SBCAP;
    for (int i = tid; i < len; i += 1024)
        atomicAdd(&cnt[seg[i] & 255], 1);
    __syncthreads();

    int v = 0;
    if (tid < 256) { v = cnt[tid]; tmp[tid] = v; }
    __syncthreads();
    for (int o = 1; o < 256; o <<= 1) {
        int t = (tid >= o && tid < 256) ? tmp[tid - o] : 0;
        __syncthreads();
        if (tid < 256) tmp[tid] += t;
        __syncthreads();
    }
    if (tid < 256) off[tid] = tmp[tid] - v;  // exclusive
    if (tid == 255) base_sh = atomicAdd(gcounter, tmp[255]);
    __syncthreads();

    const int base = base_sh;
    if (tid < 256) {
        int node = (sb << SBSH) + tid;
        if (node < n) {
            int r0 = base + off[tid];
            rowptr[node] = r0;
            rowend[node] = r0 + v;
            dinv[node] = rsqrtf((float)v + 1.0f);  // +1 self-loop
        }
    }
    __syncthreads();

    for (int i = tid; i < len; i += 1024) {
        int rec = seg[i];
        int lpos = atomicAdd(&off[rec & 255], 1);
        src_sorted[base + lpos] = rec >> SBSH;
    }
}

// ====== 16-wave single-pass MFMA tiles (verified R4/R5/R10) ======
template <int KP, int KOUT, int NTY, bool BIAS, bool OUT_BF16, int OSTR>
__device__ __forceinline__ void mfma_tiles16(const unsigned short* Abf, const unsigned short* Wt,
                                             const float* __restrict__ bias, void* __restrict__ C,
                                             int n, int row0) {
    constexpr int APAD  = KP + 8;
    constexpr int NKC   = KP / 32;
    constexpr int TQ    = (NTY + 1) / 2;
    constexpr int NTALL = (KOUT + 15) / 16;

    const int tid  = threadIdx.x;
    const int lane = tid & 63;
    const int w    = tid >> 6;          // 0..15
    const int m0   = (w >> 1) * 16;     // 16-row strip per wave pair
    const int t0   = (w & 1) * TQ;
    const int lm   = lane & 15;
    const int quad = lane >> 4;
    const int tcnt = (NTALL - t0 < TQ) ? (NTALL - t0) : TQ;

    f32x4 acc[TQ];
    #pragma unroll
    for (int t = 0; t < TQ; ++t) acc[t] = (f32x4)(0.f);

    for (int kt = 0; kt < NKC; ++kt) {
        short8 a = *(const short8*)&Abf[(m0 + lm) * APAD + kt * 32 + quad * 8];
        short8 b[TQ];
        #pragma unroll
        for (int t = 0; t < TQ; ++t)
            if (t < tcnt)
                b[t] = *(const short8*)&Wt[((t0 + t) * 16 + lm) * APAD + kt * 32 + quad * 8];
        #pragma unroll
        for (int t = 0; t < TQ; ++t)
            if (t < tcnt)
                acc[t] = __builtin_amdgcn_mfma_f32_16x16x32_bf16(a, b[t], acc[t], 0, 0, 0);
    }

    #pragma unroll
    for (int t = 0; t < TQ; ++t) {
        if (t >= tcnt) continue;
        int col = (t0 + t) * 16 + lm;
        if (col >= KOUT) continue;
        float bv = 0.f;
        if constexpr (BIAS) bv = bias[col];
        #pragma unroll
        for (int rg = 0; rg < 4; ++rg) {
            int row = row0 + m0 + quad * 4 + rg;
            if (row < n) {
                float v = acc[t][rg] + bv;
                if constexpr (OUT_BF16)
                    ((unsigned short*)C)[(size_t)row * OSTR + col] = f2bf(v);
                else
                    ((float*)C)[(size_t)row * OSTR + col] = v;
            }
        }
    }
}

// ====== fused gather-aggregation + GEMM: R10 structure (128 rows / 1024 thr) + unroll-8 ======
// Unroll-8 consumes edges sequentially in CSR order -> bit-identical to R10's unroll-4.
template <int FAGG, int NG, int HSTR, int KIN, int KOUT, int NTY, bool GBIAS, bool OUT_BF16, int OSTR>
__global__ __launch_bounds__(1024) void k_agg_gemm(const unsigned short* __restrict__ h,
                                                   const int* __restrict__ rowptr,
                                                   const int* __restrict__ rowend,
                                                   const int* __restrict__ src_sorted,
                                                   const float* __restrict__ dinv,
                                                   const float* __restrict__ ab,
                                                   const float* __restrict__ W,
                                                   const float* __restrict__ gb,
                                                   void* __restrict__ C, int n) {
    constexpr int KP   = ((KIN + 31) / 32) * 32;
    constexpr int APAD = KP + 8;
    constexpr int NTC  = NTY * 16;
    static_assert(NTC >= ((KOUT + 15) / 16) * 16, "single-pass Wt");
    static_assert(NG * 8 <= KP, "agg cols fit A tile");

    __shared__ __attribute__((aligned(16))) unsigned short Abf[128 * APAD];
    __shared__ __attribute__((aligned(16))) unsigned short Wt[NTC * APAD];
    __shared__ int   rp0[128], rc[128];   // per-row CSR start / count (absolute indices)
    __shared__ float sdi[128];            // per-row dinv[i]

    const int tid  = threadIdx.x;
    const int row0 = blockIdx.x * 128;

    // ---- (1) stage Wt (+k pads) + per-row scalars ----
    for (int idx = tid; idx < KIN * NTC; idx += 1024) {
        int k = idx / NTC;
        int c = idx - k * NTC;
        float v = (c < KOUT) ? W[(size_t)k * KOUT + c] : 0.f;
        Wt[c * APAD + k] = f2bf(v);
    }
    if constexpr (KP > KIN) {
        constexpr int PADW = KP - KIN;
        for (int idx = tid; idx < NTC * PADW; idx += 1024) {
            int c = idx / PADW;
            Wt[c * APAD + KIN + (idx - c * PADW)] = 0;
        }
    }
    if (tid < 128) {
        int i = row0 + tid;
        if (i < n) {
            int r0 = rowptr[i];
            rp0[tid] = r0;
            rc[tid]  = rowend[i] - r0;
            sdi[tid] = dinv[i];
        } else {
            rp0[tid] = 0; rc[tid] = 0; sdi[tid] = 0.f;
        }
    }
    __syncthreads();

    // ---- (2) gather-aggregate into Abf (bit-exact CSR-order accumulation) ----
    for (int idx = tid; idx < 128 * NG; idx += 1024) {
        int r = idx / NG;
        int g = idx - r * NG;
        const int co = g * 8;
        int i = row0 + r;
        u16x8 o;
        #pragma unroll
        for (int j = 0; j < 8; ++j) o[j] = 0;
        if (i < n) {
            const unsigned short* hp = h + co;
            float a[8];
            #pragma unroll
            for (int j = 0; j < 8; ++j) a[j] = 0.f;
            int e = rp0[r];
            const int end = e + rc[r];
            for (; e + 7 < end; e += 8) {
                int s0 = src_sorted[e],     s1 = src_sorted[e + 1];
                int s2 = src_sorted[e + 2], s3 = src_sorted[e + 3];
                int s4 = src_sorted[e + 4], s5 = src_sorted[e + 5];
                int s6 = src_sorted[e + 6], s7 = src_sorted[e + 7];
                u16x8 u0 = *(const u16x8*)&hp[(size_t)s0 * HSTR];
                u16x8 u1 = *(const u16x8*)&hp[(size_t)s1 * HSTR];
                u16x8 u2 = *(const u16x8*)&hp[(size_t)s2 * HSTR];
                u16x8 u3 = *(const u16x8*)&hp[(size_t)s3 * HSTR];
                u16x8 u4 = *(const u16x8*)&hp[(size_t)s4 * HSTR];
                u16x8 u5 = *(const u16x8*)&hp[(size_t)s5 * HSTR];
                u16x8 u6 = *(const u16x8*)&hp[(size_t)s6 * HSTR];
                u16x8 u7 = *(const u16x8*)&hp[(size_t)s7 * HSTR];
                float n0 = dinv[s0], n1 = dinv[s1], n2 = dinv[s2], n3 = dinv[s3];
                float n4 = dinv[s4], n5 = dinv[s5], n6 = dinv[s6], n7 = dinv[s7];
                #pragma unroll
                for (int j = 0; j < 8; ++j) {
                    a[j] = fmaf(bf2f(u0[j]), n0, a[j]);
                    a[j] = fmaf(bf2f(u1[j]), n1, a[j]);
                    a[j] = fmaf(bf2f(u2[j]), n2, a[j]);
                    a[j] = fmaf(bf2f(u3[j]), n3, a[j]);
                    a[j] = fmaf(bf2f(u4[j]), n4, a[j]);
                    a[j] = fmaf(bf2f(u5[j]), n5, a[j]);
                    a[j] = fmaf(bf2f(u6[j]), n6, a[j]);
                    a[j] = fmaf(bf2f(u7[j]), n7, a[j]);
                }
            }
            for (; e + 3 < end; e += 4) {
                int s0 = src_sorted[e],     s1 = src_sorted[e + 1];
                int s2 = src_sorted[e + 2], s3 = src_sorted[e + 3];
                u16x8 u0 = *(const u16x8*)&hp[(size_t)s0 * HSTR];
                u16x8 u1 = *(const u16x8*)&hp[(size_t)s1 * HSTR];
                u16x8 u2 = *(const u16x8*)&hp[(size_t)s2 * HSTR];
                u16x8 u3 = *(const u16x8*)&hp[(size_t)s3 * HSTR];
                float n0 = dinv[s0], n1 = dinv[s1], n2 = dinv[s2], n3 = dinv[s3];
                #pragma unroll
                for (int j = 0; j < 8; ++j) {
                    a[j] = fmaf(bf2f(u0[j]), n0, a[j]);
                    a[j] = fmaf(bf2f(u1[j]), n1, a[j]);
                    a[j] = fmaf(bf2f(u2[j]), n2, a[j]);
                    a[j] = fmaf(bf2f(u3[j]), n3, a[j]);
                }
            }
            for (; e < end; ++e) {
                int s = src_sorted[e];
                u16x8 u = *(const u16x8*)&hp[(size_t)s * HSTR];
                float nn = dinv[s];
                #pragma unroll
                for (int j = 0; j < 8; ++j) a[j] = fmaf(bf2f(u[j]), nn, a[j]);
            }
            float di = sdi[r];
            u16x8 hs = *(const u16x8*)&hp[(size_t)i * HSTR];
            #pragma unroll
            for (int j = 0; j < 8; ++j) {
                int col = co + j;
                float bj = (col < FAGG) ? ab[col] : 0.f;
                float vv = fmaf(di, fmaf(di, bf2f(hs[j]), a[j]), bj);
                o[j] = f2bf(fmaxf(vv, 0.f));
            }
        }
        *(u16x8*)&Abf[r * APAD + co] = o;
    }
    if constexpr (KP > NG * 8) {             // zero A pad cols [NG*8, KP)
        constexpr int PW = KP - NG * 8;
        for (int idx = tid; idx < 128 * PW; idx += 1024) {
            int r = idx / PW;
            Abf[r * APAD + NG * 8 + (idx - r * PW)] = 0;
        }
    }
    __syncthreads();

    // ---- (3) GEMM ----
    mfma_tiles16<KP, KOUT, NTY, GBIAS, OUT_BF16, OSTR>(Abf, Wt, gb, C, n, row0);
}

extern "C" void kernel_launch(void* const* d_in, const int* in_sizes, int n_in,
                              void* d_out, int out_size, void* d_ws, size_t ws_size,
                              hipStream_t stream) {
    const float* x  = (const float*)d_in[0];
    const int*   ei = (const int*)d_in[1];
    const float* W1 = (const float*)d_in[2];
    const float* b1 = (const float*)d_in[3];
    const float* W2 = (const float*)d_in[4];
    const float* b2 = (const float*)d_in[5];
    const float* Wc = (const float*)d_in[6];
    const float* bc = (const float*)d_in[7];
    float* out = (float*)d_out;

    const int N = in_sizes[0] / FIN;
    const int E = in_sizes[1] / 2;
    const int* src = ei;
    const int* dst = ei + E;
    const int NSB = (N + 255) >> SBSH;       // 196
    const int SCB = (E + EPB - 1) / EPB;     // 391

    auto align = [](size_t v) { return (v + 255) & ~(size_t)255; };
    char* ws = (char*)d_ws;
    const size_t cur_bytes = align((size_t)256 * CSTR * 4 + 256);
    int*   gcur       = (int*)ws;   ws += cur_bytes;
    int*   gcounter   = gcur + 256 * CSTR;   // inside the memset region
    int*   arena      = (int*)ws;   ws += align((size_t)NSB * SBCAP * 4);
    int*   rowptr     = (int*)ws;   ws += align((size_t)N * 4);
    int*   rowend     = (int*)ws;   ws += align((size_t)N * 4);
    int*   src_sorted = (int*)ws;   ws += align((size_t)E * 4);
    float* dinv       = (float*)ws; ws += align((size_t)N * 4);
    unsigned short* h1 = (unsigned short*)ws; ws += align((size_t)N * H1STR * 2);
    unsigned short* h2 = (unsigned short*)ws; ws += align((size_t)N * FEMB * 2);

    const int nmb = (N + 127) / 128;         // 391 row-tiles

    // 1) zero cursors + gcounter
    hipMemsetAsync(gcur, 0, cur_bytes, stream);

    // 2) merged: edge scatter (blocks [0,SCB)) || GEMM1 h1 = x@W1 (blocks [SCB,SCB+nmb))
    k_front<<<SCB + nmb, 256, 0, stream>>>(src, dst, gcur, arena, E, NSB, SCB, x, W1, h1, N);

    // 3) per-super-bucket sort -> rowptr/rowend/dinv/src_sorted
    k_bucket_sort<<<NSB, 1024, 0, stream>>>(arena, gcur, gcounter, rowptr, rowend, dinv, src_sorted, N);

    // 4) fused: a1 = relu(agg(h1)+b1) -> LDS; h2 = a1 @ W2 (bf16, stride FEMB)
    k_agg_gemm<FHID, 13, H1STR, FHID, FEMB, 4, false, true, FEMB>
        <<<nmb, 1024, 0, stream>>>(h1, rowptr, rowend, src_sorted, dinv, b1, W2, nullptr, h2, N);

    // 5) fused: a2 = relu(agg(h2)+b2) -> LDS; out = a2 @ Wc + bc (fp32)
    k_agg_gemm<FEMB, 8, FEMB, FEMB, NCLS, 3, true, false, NCLS>
        <<<nmb, 1024, 0, stream>>>(h2, rowptr, rowend, src_sorted, dinv, b2, Wc, bc, out, N);
}

// Round 13
// 180.889 us; speedup vs baseline: 1.0828x; 1.0643x over previous
//
#include <hip/hip_runtime.h>

#define FIN 100
#define FHID 100
#define FEMB 64
#define NCLS 40
#define H1STR 128             // h1 row stride: 256B, line-ALIGNED (R12-measured: FETCH 90->81 MB)

#define SBSH 8                // 256 nodes per super-bucket
#define CAPB 24               // LDS bin capacity per block (EPB=2048: mean 10.4 -> overflow ~1e-4, order-stable)
#define SBCAP 4608            // per-super-bucket arena cap: mean 4096 + 8 sigma
#define CSTR 16               // cursor stride in ints
#define EPB 2048              // edges per scatter block (R5 value)

typedef __attribute__((ext_vector_type(8))) short short8;          // MFMA A/B frag
typedef __attribute__((ext_vector_type(8))) unsigned short u16x8;  // 16B bf16 gather
typedef __attribute__((ext_vector_type(4))) float f32x4;           // MFMA C/D frag

// ---------- bf16 helpers (RNE) ----------
__device__ inline unsigned short f2bf(float f) {
    unsigned u = __float_as_uint(f);
    u += 0x7FFFu + ((u >> 16) & 1u);
    return (unsigned short)(u >> 16);
}
__device__ inline float bf2f(unsigned short s) {
    return __uint_as_float((unsigned)s << 16);
}

// ====== 4-wave MFMA tiles (GEMM1 inside k_front; 256 threads, multi-pass) ======
template <int KP, int KOUT, int NTY, bool BIAS, bool OUT_BF16, int OSTR>
__device__ __forceinline__ void mfma_tiles4(const unsigned short* Abf, const unsigned short* Wt,
                                            const float* __restrict__ bias, void* __restrict__ C,
                                            int n, int row0, int tb) {
    constexpr int APAD  = KP + 8;
    constexpr int NKC   = KP / 32;
    constexpr int TQ    = (NTY + 1) / 2;
    constexpr int NTALL = (KOUT + 15) / 16;

    const int tid  = threadIdx.x;
    const int lane = tid & 63;
    const int w    = tid >> 6;
    const int m0   = (w >> 1) * 64;
    const int t0   = (w & 1) * TQ;
    const int lm   = lane & 15;
    const int quad = lane >> 4;

    const int ntloc = (NTALL - tb < NTY) ? (NTALL - tb) : NTY;
    const int tcnt  = (ntloc - t0 < TQ) ? (ntloc - t0) : TQ;

    f32x4 acc[4][TQ];
    #pragma unroll
    for (int i = 0; i < 4; ++i)
        #pragma unroll
        for (int t = 0; t < TQ; ++t)
            acc[i][t] = (f32x4)(0.f);

    for (int kt = 0; kt < NKC; ++kt) {
        short8 a[4], b[TQ];
        #pragma unroll
        for (int i = 0; i < 4; ++i)
            a[i] = *(const short8*)&Abf[(m0 + i * 16 + lm) * APAD + kt * 32 + quad * 8];
        #pragma unroll
        for (int t = 0; t < TQ; ++t)
            if (t < tcnt)
                b[t] = *(const short8*)&Wt[((t0 + t) * 16 + lm) * APAD + kt * 32 + quad * 8];
        #pragma unroll
        for (int i = 0; i < 4; ++i)
            #pragma unroll
            for (int t = 0; t < TQ; ++t)
                if (t < tcnt)
                    acc[i][t] = __builtin_amdgcn_mfma_f32_16x16x32_bf16(a[i], b[t], acc[i][t], 0, 0, 0);
    }

    #pragma unroll
    for (int t = 0; t < TQ; ++t) {
        if (t >= tcnt) continue;
        int col = (tb + t0 + t) * 16 + lm;
        if (col >= KOUT) continue;
        float bv = 0.f;
        if constexpr (BIAS) bv = bias[col];
        #pragma unroll
        for (int i = 0; i < 4; ++i) {
            #pragma unroll
            for (int rg = 0; rg < 4; ++rg) {
                int row = row0 + m0 + i * 16 + quad * 4 + rg;
                if (row < n) {
                    float v = acc[i][t][rg] + bv;
                    if constexpr (OUT_BF16)
                        ((unsigned short*)C)[(size_t)row * OSTR + col] = f2bf(v);
                    else
                        ((float*)C)[(size_t)row * OSTR + col] = v;
                }
            }
        }
    }
}

// ====== GEMM1 body: stage fp32 A -> bf16 LDS, multi-pass Wt, 256 threads ======
template <int KIN, int KOUT, int NTY, bool OUT_BF16, int ASTR, int OSTR>
__device__ __forceinline__ void gemm_body(const void* __restrict__ A, const float* __restrict__ W,
                                          void* __restrict__ C, int n, int bid, char* smem) {
    constexpr int KP    = ((KIN + 31) / 32) * 32;
    constexpr int NTALL = (KOUT + 15) / 16;
    constexpr int NTC   = NTY * 16;
    constexpr int APAD  = KP + 8;
    constexpr int KQ4   = KIN / 4;

    unsigned short* Abf = (unsigned short*)smem;               // 128 * APAD
    unsigned short* Wt  = Abf + 128 * APAD;                    // NTC * APAD

    const int row0 = bid * 128;
    const int tid  = threadIdx.x;

    {   // stage A (fp32 -> bf16)
        const float* Af = (const float*)A;
        for (int idx = tid; idx < 128 * KQ4; idx += 256) {
            int r = idx / KQ4;
            int kq = idx - r * KQ4;
            float4 v = make_float4(0.f, 0.f, 0.f, 0.f);
            if (row0 + r < n) v = ((const float4*)(Af + (size_t)(row0 + r) * ASTR))[kq];
            ushort4 o;
            o.x = f2bf(v.x); o.y = f2bf(v.y); o.z = f2bf(v.z); o.w = f2bf(v.w);
            *(ushort4*)&Abf[r * APAD + kq * 4] = o;
        }
    }
    if constexpr (KP > KIN) {
        constexpr int PADW = KP - KIN;
        for (int idx = tid; idx < 128 * PADW; idx += 256) {
            int r = idx / PADW;
            Abf[r * APAD + KIN + (idx - r * PADW)] = 0;
        }
    }
    // zero output pad columns (downstream u16x8 gathers read exact zeros)
    if constexpr (OUT_BF16 && (OSTR > KOUT)) {
        constexpr int PW = OSTR - KOUT;
        for (int idx = tid; idx < 128 * PW; idx += 256) {
            int r = idx / PW;
            int c = idx - r * PW;
            if (row0 + r < n)
                ((unsigned short*)C)[(size_t)(row0 + r) * OSTR + KOUT + c] = 0;
        }
    }

    for (int tb = 0; tb < NTALL; tb += NTY) {
        for (int idx = tid; idx < KIN * NTC; idx += 256) {
            int k = idx / NTC;
            int c = idx - k * NTC;
            int gc = tb * 16 + c;
            float v = (gc < KOUT) ? W[(size_t)k * KOUT + gc] : 0.f;
            Wt[c * APAD + k] = f2bf(v);
        }
        if constexpr (KP > KIN) {
            constexpr int PADW = KP - KIN;
            for (int idx = tid; idx < NTC * PADW; idx += 256) {
                int c = idx / PADW;
                Wt[c * APAD + KIN + (idx - c * PADW)] = 0;
            }
        }
        __syncthreads();
        mfma_tiles4<KP, KOUT, NTY, false, OUT_BF16, OSTR>(Abf, Wt, nullptr, C, n, row0, tb);
        __syncthreads();
    }
}

// ====== merged front: edge scatter-binning (blocks [0,scb)) || GEMM1 (blocks [scb,scb+nmb)) ======
// R5-verbatim.
#define SMEM_FRONT ((128 + 64) * (128 + 8) * 2)   // 52224B; gemm1 is the larger user
__global__ __launch_bounds__(256) void k_front(const int* __restrict__ src,
                                               const int* __restrict__ dst,
                                               int* __restrict__ gcur,
                                               int* __restrict__ arena,
                                               int E, int nsb, int scb,
                                               const float* __restrict__ x,
                                               const float* __restrict__ W1,
                                               unsigned short* __restrict__ h1, int n) {
    __shared__ __attribute__((aligned(16))) char smem[SMEM_FRONT];
    static_assert(SMEM_FRONT >= (int)(256 * CAPB * 4 + 2 * 256 * 4), "scatter fits");
    if ((int)blockIdx.x < scb) {
        int* bins  = (int*)smem;            // 256*CAPB
        int* bcnt  = bins + 256 * CAPB;     // 256
        int* pbase = bcnt + 256;            // 256
        const int tid = threadIdx.x;
        bcnt[tid] = 0;
        __syncthreads();

        const int e0 = blockIdx.x * EPB;
        for (int k = 0; k < EPB / 256; ++k) {
            int e = e0 + k * 256 + tid;
            if (e < E) {
                int d = dst[e];
                int sb = d >> SBSH;
                int rec = (src[e] << SBSH) | (d & 255);
                int c = atomicAdd(&bcnt[sb], 1);
                if (c < CAPB) {
                    bins[sb * CAPB + c] = rec;
                } else {  // rare overflow: direct global append
                    int p = atomicAdd(&gcur[sb * CSTR], 1);
                    if (p < SBCAP) arena[(size_t)sb * SBCAP + p] = rec;
                }
            }
        }
        __syncthreads();

        if (tid < nsb) {
            int c = bcnt[tid];
            if (c > CAPB) c = CAPB;
            pbase[tid] = (c > 0) ? atomicAdd(&gcur[tid * CSTR], c) : 0;
        }
        __syncthreads();

        const int wv = tid >> 6, lane = tid & 63;
        for (int sb = wv; sb < nsb; sb += 4) {
            int c = bcnt[sb];
            if (c > CAPB) c = CAPB;
            int p = pbase[sb];
            if (lane < c && p + lane < SBCAP)
                arena[(size_t)sb * SBCAP + p + lane] = bins[sb * CAPB + lane];
        }
    } else {
        gemm_body<FIN, FHID, 4, true, FIN, H1STR>(x, W1, h1, n, (int)blockIdx.x - scb, smem);
    }
}

// ====== per-super-bucket sort: 1024 threads (verified R1/R5/R10) ======
__global__ __launch_bounds__(1024) void k_bucket_sort(const int* __restrict__ arena,
                                                      const int* __restrict__ gcur,
                                                      int* __restrict__ gcounter,
                                                      int* __restrict__ rowptr,
                                                      int* __restrict__ rowend,
                                                      float* __restrict__ dinv,
                                                      int* __restrict__ src_sorted, int n) {
    const int sb = blockIdx.x;
    const int tid = threadIdx.x;
    __shared__ int cnt[256], off[256], tmp[256];
    __shared__ int base_sh;
    if (tid < 256) cnt[tid] = 0;
    __syncthreads();

    int len = gcur[sb * CSTR];
    if (len > SBCAP) len = SBCAP;
    const int* seg = arena + (size_t)sb * SBCAP;
    for (int i = tid; i < len; i += 1024)
        atomicAdd(&cnt[seg[i] & 255], 1);
    __syncthreads();

    int v = 0;
    if (tid < 256) { v = cnt[tid]; tmp[tid] = v; }
    __syncthreads();
    for (int o = 1; o < 256; o <<= 1) {
        int t = (tid >= o && tid < 256) ? tmp[tid - o] : 0;
        __syncthreads();
        if (tid < 256) tmp[tid] += t;
        __syncthreads();
    }
    if (tid < 256) off[tid] = tmp[tid] - v;  // exclusive
    if (tid == 255) base_sh = atomicAdd(gcounter, tmp[255]);
    __syncthreads();

    const int base = base_sh;
    if (tid < 256) {
        int node = (sb << SBSH) + tid;
        if (node < n) {
            int r0 = base + off[tid];
            rowptr[node] = r0;
            rowend[node] = r0 + v;
            dinv[node] = rsqrtf((float)v + 1.0f);  // +1 self-loop
        }
    }
    __syncthreads();

    for (int i = tid; i < len; i += 1024) {
        int rec = seg[i];
        int lpos = atomicAdd(&off[rec & 255], 1);
        src_sorted[base + lpos] = rec >> SBSH;
    }
}

// ====== 16-wave single-pass MFMA tiles (verified R4/R5/R10) ======
template <int KP, int KOUT, int NTY, bool BIAS, bool OUT_BF16, int OSTR>
__device__ __forceinline__ void mfma_tiles16(const unsigned short* Abf, const unsigned short* Wt,
                                             const float* __restrict__ bias, void* __restrict__ C,
                                             int n, int row0) {
    constexpr int APAD  = KP + 8;
    constexpr int NKC   = KP / 32;
    constexpr int TQ    = (NTY + 1) / 2;
    constexpr int NTALL = (KOUT + 15) / 16;

    const int tid  = threadIdx.x;
    const int lane = tid & 63;
    const int w    = tid >> 6;          // 0..15
    const int m0   = (w >> 1) * 16;     // 16-row strip per wave pair
    const int t0   = (w & 1) * TQ;
    const int lm   = lane & 15;
    const int quad = lane >> 4;
    const int tcnt = (NTALL - t0 < TQ) ? (NTALL - t0) : TQ;

    f32x4 acc[TQ];
    #pragma unroll
    for (int t = 0; t < TQ; ++t) acc[t] = (f32x4)(0.f);

    for (int kt = 0; kt < NKC; ++kt) {
        short8 a = *(const short8*)&Abf[(m0 + lm) * APAD + kt * 32 + quad * 8];
        short8 b[TQ];
        #pragma unroll
        for (int t = 0; t < TQ; ++t)
            if (t < tcnt)
                b[t] = *(const short8*)&Wt[((t0 + t) * 16 + lm) * APAD + kt * 32 + quad * 8];
        #pragma unroll
        for (int t = 0; t < TQ; ++t)
            if (t < tcnt)
                acc[t] = __builtin_amdgcn_mfma_f32_16x16x32_bf16(a, b[t], acc[t], 0, 0, 0);
    }

    #pragma unroll
    for (int t = 0; t < TQ; ++t) {
        if (t >= tcnt) continue;
        int col = (t0 + t) * 16 + lm;
        if (col >= KOUT) continue;
        float bv = 0.f;
        if constexpr (BIAS) bv = bias[col];
        #pragma unroll
        for (int rg = 0; rg < 4; ++rg) {
            int row = row0 + m0 + quad * 4 + rg;
            if (row < n) {
                float v = acc[t][rg] + bv;
                if constexpr (OUT_BF16)
                    ((unsigned short*)C)[(size_t)row * OSTR + col] = f2bf(v);
                else
                    ((float*)C)[(size_t)row * OSTR + col] = v;
            }
        }
    }
}

// ====== fused gather-aggregation + GEMM: R10 structure (128 rows / 1024 thr, unroll-4) ======
// Only delta vs R10's verified kernel: HSTR=128 (line-aligned rows; arithmetic unchanged).
template <int FAGG, int NG, int HSTR, int KIN, int KOUT, int NTY, bool GBIAS, bool OUT_BF16, int OSTR>
__global__ __launch_bounds__(1024) void k_agg_gemm(const unsigned short* __restrict__ h,
                                                   const int* __restrict__ rowptr,
                                                   const int* __restrict__ rowend,
                                                   const int* __restrict__ src_sorted,
                                                   const float* __restrict__ dinv,
                                                   const float* __restrict__ ab,
                                                   const float* __restrict__ W,
                                                   const float* __restrict__ gb,
                                                   void* __restrict__ C, int n) {
    constexpr int KP   = ((KIN + 31) / 32) * 32;
    constexpr int APAD = KP + 8;
    constexpr int NTC  = NTY * 16;
    static_assert(NTC >= ((KOUT + 15) / 16) * 16, "single-pass Wt");
    static_assert(NG * 8 <= KP, "agg cols fit A tile");

    __shared__ __attribute__((aligned(16))) unsigned short Abf[128 * APAD];
    __shared__ __attribute__((aligned(16))) unsigned short Wt[NTC * APAD];
    __shared__ int   rp0[128], rc[128];   // per-row CSR start / count (absolute indices)
    __shared__ float sdi[128];            // per-row dinv[i]

    const int tid  = threadIdx.x;
    const int row0 = blockIdx.x * 128;

    // ---- (1) stage Wt (+k pads) + per-row scalars ----
    for (int idx = tid; idx < KIN * NTC; idx += 1024) {
        int k = idx / NTC;
        int c = idx - k * NTC;
        float v = (c < KOUT) ? W[(size_t)k * KOUT + c] : 0.f;
        Wt[c * APAD + k] = f2bf(v);
    }
    if constexpr (KP > KIN) {
        constexpr int PADW = KP - KIN;
        for (int idx = tid; idx < NTC * PADW; idx += 1024) {
            int c = idx / PADW;
            Wt[c * APAD + KIN + (idx - c * PADW)] = 0;
        }
    }
    if (tid < 128) {
        int i = row0 + tid;
        if (i < n) {
            int r0 = rowptr[i];
            rp0[tid] = r0;
            rc[tid]  = rowend[i] - r0;
            sdi[tid] = dinv[i];
        } else {
            rp0[tid] = 0; rc[tid] = 0; sdi[tid] = 0.f;
        }
    }
    __syncthreads();

    // ---- (2) gather-aggregate into Abf (bit-exact CSR-order accumulation, unroll-4) ----
    for (int idx = tid; idx < 128 * NG; idx += 1024) {
        int r = idx / NG;
        int g = idx - r * NG;
        const int co = g * 8;
        int i = row0 + r;
        u16x8 o;
        #pragma unroll
        for (int j = 0; j < 8; ++j) o[j] = 0;
        if (i < n) {
            const unsigned short* hp = h + co;
            float a[8];
            #pragma unroll
            for (int j = 0; j < 8; ++j) a[j] = 0.f;
            int e = rp0[r];
            const int end = e + rc[r];
            for (; e + 3 < end; e += 4) {
                int s0 = src_sorted[e],     s1 = src_sorted[e + 1];
                int s2 = src_sorted[e + 2], s3 = src_sorted[e + 3];
                u16x8 u0 = *(const u16x8*)&hp[(size_t)s0 * HSTR];
                u16x8 u1 = *(const u16x8*)&hp[(size_t)s1 * HSTR];
                u16x8 u2 = *(const u16x8*)&hp[(size_t)s2 * HSTR];
                u16x8 u3 = *(const u16x8*)&hp[(size_t)s3 * HSTR];
                float n0 = dinv[s0], n1 = dinv[s1], n2 = dinv[s2], n3 = dinv[s3];
                #pragma unroll
                for (int j = 0; j < 8; ++j) {
                    a[j] = fmaf(bf2f(u0[j]), n0, a[j]);
                    a[j] = fmaf(bf2f(u1[j]), n1, a[j]);
                    a[j] = fmaf(bf2f(u2[j]), n2, a[j]);
                    a[j] = fmaf(bf2f(u3[j]), n3, a[j]);
                }
            }
            for (; e < end; ++e) {
                int s = src_sorted[e];
                u16x8 u = *(const u16x8*)&hp[(size_t)s * HSTR];
                float nn = dinv[s];
                #pragma unroll
                for (int j = 0; j < 8; ++j) a[j] = fmaf(bf2f(u[j]), nn, a[j]);
            }
            float di = sdi[r];
            u16x8 hs = *(const u16x8*)&hp[(size_t)i * HSTR];
            #pragma unroll
            for (int j = 0; j < 8; ++j) {
                int col = co + j;
                float bj = (col < FAGG) ? ab[col] : 0.f;
                float vv = fmaf(di, fmaf(di, bf2f(hs[j]), a[j]), bj);
                o[j] = f2bf(fmaxf(vv, 0.f));
            }
        }
        *(u16x8*)&Abf[r * APAD + co] = o;
    }
    if constexpr (KP > NG * 8) {             // zero A pad cols [NG*8, KP)
        constexpr int PW = KP - NG * 8;
        for (int idx = tid; idx < 128 * PW; idx += 1024) {
            int r = idx / PW;
            Abf[r * APAD + NG * 8 + (idx - r * PW)] = 0;
        }
    }
    __syncthreads();

    // ---- (3) GEMM ----
    mfma_tiles16<KP, KOUT, NTY, GBIAS, OUT_BF16, OSTR>(Abf, Wt, gb, C, n, row0);
}

extern "C" void kernel_launch(void* const* d_in, const int* in_sizes, int n_in,
                              void* d_out, int out_size, void* d_ws, size_t ws_size,
                              hipStream_t stream) {
    const float* x  = (const float*)d_in[0];
    const int*   ei = (const int*)d_in[1];
    const float* W1 = (const float*)d_in[2];
    const float* b1 = (const float*)d_in[3];
    const float* W2 = (const float*)d_in[4];
    const float* b2 = (const float*)d_in[5];
    const float* Wc = (const float*)d_in[6];
    const float* bc = (const float*)d_in[7];
    float* out = (float*)d_out;

    const int N = in_sizes[0] / FIN;
    const int E = in_sizes[1] / 2;
    const int* src = ei;
    const int* dst = ei + E;
    const int NSB = (N + 255) >> SBSH;       // 196
    const int SCB = (E + EPB - 1) / EPB;     // 391

    auto align = [](size_t v) { return (v + 255) & ~(size_t)255; };
    char* ws = (char*)d_ws;
    const size_t cur_bytes = align((size_t)256 * CSTR * 4 + 256);
    int*   gcur       = (int*)ws;   ws += cur_bytes;
    int*   gcounter   = gcur + 256 * CSTR;   // inside the memset region
    int*   arena      = (int*)ws;   ws += align((size_t)NSB * SBCAP * 4);
    int*   rowptr     = (int*)ws;   ws += align((size_t)N * 4);
    int*   rowend     = (int*)ws;   ws += align((size_t)N * 4);
    int*   src_sorted = (int*)ws;   ws += align((size_t)E * 4);
    float* dinv       = (float*)ws; ws += align((size_t)N * 4);
    unsigned short* h1 = (unsigned short*)ws; ws += align((size_t)N * H1STR * 2);
    unsigned short* h2 = (unsigned short*)ws; ws += align((size_t)N * FEMB * 2);

    const int nmb = (N + 127) / 128;         // 391 row-tiles

    // 1) zero cursors + gcounter
    hipMemsetAsync(gcur, 0, cur_bytes, stream);

    // 2) merged: edge scatter (blocks [0,SCB)) || GEMM1 h1 = x@W1 (blocks [SCB,SCB+nmb))
    k_front<<<SCB + nmb, 256, 0, stream>>>(src, dst, gcur, arena, E, NSB, SCB, x, W1, h1, N);

    // 3) per-super-bucket sort -> rowptr/rowend/dinv/src_sorted
    k_bucket_sort<<<NSB, 1024, 0, stream>>>(arena, gcur, gcounter, rowptr, rowend, dinv, src_sorted, N);

    // 4) fused: a1 = relu(agg(h1)+b1) -> LDS; h2 = a1 @ W2 (bf16, stride FEMB)
    k_agg_gemm<FHID, 13, H1STR, FHID, FEMB, 4, false, true, FEMB>
        <<<nmb, 1024, 0, stream>>>(h1, rowptr, rowend, src_sorted, dinv, b1, W2, nullptr, h2, N);

    // 5) fused: a2 = relu(agg(h2)+b2) -> LDS; out = a2 @ Wc + bc (fp32)
    k_agg_gemm<FEMB, 8, FEMB, FEMB, NCLS, 3, true, false, NCLS>
        <<<nmb, 1024, 0, stream>>>(h2, rowptr, rowend, src_sorted, dinv, b2, Wc, bc, out, N);
}